// Round 5
// baseline (319.051 us; speedup 1.0000x reference)
//
#include <hip/hip_runtime.h>
#include <hip/hip_bf16.h>

#define N_GRAPHS 128
#define HID 96
#define OUT_DIM 10
#define CAP 64   // per-node in-edge bucket; deg ~ Poisson(16), P(>=64) ~ 1e-22/node
#define TROW 128 // fp8 row pitch, padded 96 -> 128: one aligned 128B line per row

typedef __attribute__((ext_vector_type(8))) short short8;
typedef __attribute__((ext_vector_type(4))) float f32x4;
typedef __attribute__((ext_vector_type(2))) float f32x2;

// fp32 -> bf16 round-to-nearest-even
__device__ inline unsigned short f2bf(float f) {
    union { float f; unsigned u; } x;
    x.f = f;
    unsigned r = x.u + 0x7FFFu + ((x.u >> 16) & 1u);
    return (unsigned short)(r >> 16);
}

// fp32 -> fp8 e4m3 (OCP, HW convert), one byte
__device__ inline unsigned char f2fp8(float v) {
    int p = __builtin_amdgcn_cvt_pk_fp8_f32(v, v, 0, false);
    return (unsigned char)(p & 0xff);
}

// unpack 16 fp8 (uint4) -> 16 floats
__device__ inline void unpack16_fp8(uint4 v, float* o) {
    f32x2 a0 = __builtin_amdgcn_cvt_pk_f32_fp8((int)v.x, false);
    f32x2 a1 = __builtin_amdgcn_cvt_pk_f32_fp8((int)v.x, true);
    f32x2 b0 = __builtin_amdgcn_cvt_pk_f32_fp8((int)v.y, false);
    f32x2 b1 = __builtin_amdgcn_cvt_pk_f32_fp8((int)v.y, true);
    f32x2 c0 = __builtin_amdgcn_cvt_pk_f32_fp8((int)v.z, false);
    f32x2 c1 = __builtin_amdgcn_cvt_pk_f32_fp8((int)v.z, true);
    f32x2 d0 = __builtin_amdgcn_cvt_pk_f32_fp8((int)v.w, false);
    f32x2 d1 = __builtin_amdgcn_cvt_pk_f32_fp8((int)v.w, true);
    o[0] = a0.x;  o[1] = a0.y;  o[2] = a1.x;  o[3] = a1.y;
    o[4] = b0.x;  o[5] = b0.y;  o[6] = b1.x;  o[7] = b1.y;
    o[8] = c0.x;  o[9] = c0.y;  o[10] = c1.x; o[11] = c1.y;
    o[12] = d0.x; o[13] = d0.y; o[14] = d1.x; o[15] = d1.y;
}

// ============ XCD-partitioned CSR bucket fill + per-graph node counts ============
// block b: partition p = b&7 (dst range [N*p/8, N*(p+1)/8)), edge chunk b>>3 (2048 edges).
__global__ __launch_bounds__(256) void fill_kernel(const int* __restrict__ rowi,
                                                   const int* __restrict__ coli,
                                                   const int* __restrict__ batch,
                                                   int* __restrict__ cnt,
                                                   int* __restrict__ gcount,
                                                   unsigned short* __restrict__ srcs,
                                                   int E, int N) {
    const int part = blockIdx.x & 7;
    const int chunk = blockIdx.x >> 3;
    const int base = chunk * 2048;
    const int plo = (int)(((long long)N * part) >> 3);
    const int phi = (int)(((long long)N * (part + 1)) >> 3);
#pragma unroll
    for (int it = 0; it < 8; ++it) {
        int e = base + it * 256 + threadIdx.x;
        if (e < E) {
            int c = coli[e];
            if (c >= plo && c < phi) {
                int pos = atomicAdd(&cnt[c], 1);
                if (pos < CAP) srcs[(size_t)c * CAP + pos] = (unsigned short)rowi[e];
            }
        }
    }
    // per-graph node histogram (batch sorted -> wave-coalesced atomics)
    const int gstride = gridDim.x * 256;
    for (int i = blockIdx.x * 256 + threadIdx.x; i < N; i += gstride)
        atomicAdd(&gcount[batch[i]], 1);
}

// ============ gemm1: Tp1[N x TROW](fp8) = d[:,None] * (x[N x 128] @ W1[128 x 96]) ============
__global__ __launch_bounds__(256) void gemm1_mfma(const float* __restrict__ X,
                                                  const float* __restrict__ W,
                                                  const int* __restrict__ cnt,
                                                  unsigned char* __restrict__ Tp, int N) {
    constexpr int K = 128;
    constexpr int P = K + 8;
    constexpr int KT = K / 32;
    __shared__ __align__(16) unsigned short Wt[96 * P];
    const int tid = threadIdx.x;
    const int row0 = blockIdx.x * 64;

    for (int idx = tid; idx < K * 96; idx += 256) {
        int k = idx / 96, n = idx - k * 96;
        Wt[n * P + k] = f2bf(W[idx]);
    }
    __syncthreads();

    const int wv = tid >> 6;
    const int lane = tid & 63;
    const int m = lane & 15;
    const int quad = lane >> 4;
    const int row = row0 + wv * 16 + m;

    short8 afrag[KT];
    if (row < N) {
        const float* Xr = X + (size_t)row * K;
#pragma unroll
        for (int t = 0; t < KT; ++t) {
            float4 a0 = *(const float4*)(Xr + t * 32 + quad * 8);
            float4 a1 = *(const float4*)(Xr + t * 32 + quad * 8 + 4);
            short8 a;
            a[0] = (short)f2bf(a0.x); a[1] = (short)f2bf(a0.y);
            a[2] = (short)f2bf(a0.z); a[3] = (short)f2bf(a0.w);
            a[4] = (short)f2bf(a1.x); a[5] = (short)f2bf(a1.y);
            a[6] = (short)f2bf(a1.z); a[7] = (short)f2bf(a1.w);
            afrag[t] = a;
        }
    } else {
#pragma unroll
        for (int t = 0; t < KT; ++t) afrag[t] = short8{0, 0, 0, 0, 0, 0, 0, 0};
    }

    f32x4 acc[6];
#pragma unroll
    for (int nt = 0; nt < 6; ++nt) acc[nt] = f32x4{0.f, 0.f, 0.f, 0.f};
#pragma unroll
    for (int t = 0; t < KT; ++t) {
#pragma unroll
        for (int nt = 0; nt < 6; ++nt) {
            short8 bfrag = *(const short8*)&Wt[(nt * 16 + m) * P + t * 32 + quad * 8];
            acc[nt] = __builtin_amdgcn_mfma_f32_16x16x32_bf16(afrag[t], bfrag, acc[nt], 0, 0, 0);
        }
    }
#pragma unroll
    for (int r = 0; r < 4; ++r) {
        int orow = row0 + wv * 16 + quad * 4 + r;
        if (orow < N) {
            float d = rsqrtf(1.0f + (float)cnt[orow]);
#pragma unroll
            for (int nt = 0; nt < 6; ++nt)
                Tp[(size_t)orow * TROW + nt * 16 + m] = f2fp8(d * acc[nt][r]);
        }
    }
}

// ============ FUSED gather1 + gemm2 — 64 nodes/block (782 blocks => ~3/CU for latency hiding) ====
// Phase A: gather layer-1 aggregate -> H tile in LDS (bf16), 6 lanes x 16B per node.
//   H[i] = relu(d_i * (sum_src Tp1[s] + Tp1[i]) + b1)   (Tp1 pre-scaled by d_src)
// Phase B: MFMA  Tp2[i] = fp8(d_i * (H[i] @ W2)); wave wv owns row-tile wv (16 rows).
__global__ __launch_bounds__(256) void gather1_gemm2(const unsigned char* __restrict__ Tp1,
                                                     const unsigned short* __restrict__ srcs,
                                                     const int* __restrict__ cnt,
                                                     const float* __restrict__ b1,
                                                     const float* __restrict__ W2,
                                                     unsigned char* __restrict__ Tp2, int N) {
    constexpr int PH = 104;  // Hs pitch (shorts)
    constexpr int PW = 104;  // Wt pitch (shorts)
    __shared__ __align__(16) unsigned short Hs[64 * PH];   // 13312 B
    __shared__ __align__(16) unsigned short Wt[96 * PW];   // 19968 B  (total 33280 B -> 4 blocks/CU LDS cap)
    const int tid = threadIdx.x;
    const int node0 = blockIdx.x * 64;

    // stage W2^T (bf16) — no dependency on phase A
    for (int idx = tid; idx < 96 * 96; idx += 256) {
        int k = idx / 96, n = idx - k * 96;
        Wt[n * PW + k] = f2bf(W2[idx]);
    }

    // Phase A: gather. 64 nodes x 6 lanes = 384 items = 1.5 x 256.
    const uint4* Trow = (const uint4*)Tp1;  // 8 uint4 per padded fp8 row (j = 0..5 used)
#pragma unroll
    for (int it = 0; it < 2; ++it) {
        int idx = it * 256 + tid;
        if (idx < 384) {
            int n = idx / 6, j = idx - n * 6;
            int i = node0 + n;
            if (i < N) {
                float acc[16], tmp[16];
                unpack16_fp8(Trow[((size_t)i << 3) + j], acc);  // self-loop term
                int ci = cnt[i];
                int e = min(ci, CAP);
                const unsigned short* sp = srcs + (size_t)i * CAP;
                int k = 0;
                for (; k + 4 <= e; k += 4) {
                    ushort4 s4 = *(const ushort4*)(sp + k);
                    uint4 v0 = Trow[((size_t)s4.x << 3) + j];
                    uint4 v1 = Trow[((size_t)s4.y << 3) + j];
                    uint4 v2 = Trow[((size_t)s4.z << 3) + j];
                    uint4 v3 = Trow[((size_t)s4.w << 3) + j];
                    unpack16_fp8(v0, tmp);
#pragma unroll
                    for (int l = 0; l < 16; ++l) acc[l] += tmp[l];
                    unpack16_fp8(v1, tmp);
#pragma unroll
                    for (int l = 0; l < 16; ++l) acc[l] += tmp[l];
                    unpack16_fp8(v2, tmp);
#pragma unroll
                    for (int l = 0; l < 16; ++l) acc[l] += tmp[l];
                    unpack16_fp8(v3, tmp);
#pragma unroll
                    for (int l = 0; l < 16; ++l) acc[l] += tmp[l];
                }
                for (; k < e; ++k) {
                    unpack16_fp8(Trow[((size_t)sp[k] << 3) + j], tmp);
#pragma unroll
                    for (int l = 0; l < 16; ++l) acc[l] += tmp[l];
                }
                float di = rsqrtf(1.0f + (float)ci);
#pragma unroll
                for (int l = 0; l < 16; ++l) {
                    float v = fmaxf(di * acc[l] + b1[j * 16 + l], 0.0f);
                    Hs[n * PH + j * 16 + l] = f2bf(v);
                }
            } else {
#pragma unroll
                for (int l = 0; l < 16; ++l) Hs[n * PH + j * 16 + l] = 0;
            }
        }
    }
    __syncthreads();

    // Phase B: 4 row-tiles of 16; wave wv owns tile wv.
    const int wv = tid >> 6;
    const int lane = tid & 63;
    const int m = lane & 15;
    const int quad = lane >> 4;
    const int lrow = wv * 16 + m;
    short8 afrag[3];
#pragma unroll
    for (int t = 0; t < 3; ++t)
        afrag[t] = *(const short8*)&Hs[lrow * PH + t * 32 + quad * 8];
    f32x4 acc[6];
#pragma unroll
    for (int nt = 0; nt < 6; ++nt) acc[nt] = f32x4{0.f, 0.f, 0.f, 0.f};
#pragma unroll
    for (int t = 0; t < 3; ++t) {
#pragma unroll
        for (int nt = 0; nt < 6; ++nt) {
            short8 bfrag = *(const short8*)&Wt[(nt * 16 + m) * PW + t * 32 + quad * 8];
            acc[nt] = __builtin_amdgcn_mfma_f32_16x16x32_bf16(afrag[t], bfrag, acc[nt], 0, 0, 0);
        }
    }
#pragma unroll
    for (int r = 0; r < 4; ++r) {
        int orow = node0 + wv * 16 + quad * 4 + r;
        if (orow < N) {
            float d = rsqrtf(1.0f + (float)cnt[orow]);
#pragma unroll
            for (int nt = 0; nt < 6; ++nt)
                Tp2[(size_t)orow * TROW + nt * 16 + m] = f2fp8(d * acc[nt][r]);
        }
    }
}

// ============ gather2 + pool: pooled[batch[i]] += d_i*(sum Tp2[s] + Tp2[i])  (b2 in head) ====
// 192 threads = 32 nodes x 6 lanes (exactly one pass); LDS per-graph reduction.
__global__ __launch_bounds__(192) void gather2_pool(const unsigned char* __restrict__ Tp,
                                                    const unsigned short* __restrict__ srcs,
                                                    const int* __restrict__ cnt,
                                                    const int* __restrict__ batch,
                                                    float* __restrict__ pooled, int N) {
    __shared__ float hl[32 * 96];
    __shared__ int g_l[32];
    const int tid = threadIdx.x;
    const int n = tid / 6;
    const int j = tid - n * 6;
    const int i = blockIdx.x * 32 + n;
    if (tid < 32) {
        int ii = blockIdx.x * 32 + tid;
        g_l[tid] = (ii < N) ? batch[ii] : -1;
    }

    float acc[16];
#pragma unroll
    for (int l = 0; l < 16; ++l) acc[l] = 0.0f;
    float di = 0.0f;
    if (i < N) {
        const uint4* Trow = (const uint4*)Tp;  // 8 uint4 per padded row
        float tmp[16];
        unpack16_fp8(Trow[((size_t)i << 3) + j], acc);  // self
        int ci = cnt[i];
        di = rsqrtf(1.0f + (float)ci);
        int e = min(ci, CAP);
        const unsigned short* sp = srcs + (size_t)i * CAP;
        int k = 0;
        for (; k + 4 <= e; k += 4) {
            ushort4 s4 = *(const ushort4*)(sp + k);
            uint4 v0 = Trow[((size_t)s4.x << 3) + j];
            uint4 v1 = Trow[((size_t)s4.y << 3) + j];
            uint4 v2 = Trow[((size_t)s4.z << 3) + j];
            uint4 v3 = Trow[((size_t)s4.w << 3) + j];
            unpack16_fp8(v0, tmp);
#pragma unroll
            for (int l = 0; l < 16; ++l) acc[l] += tmp[l];
            unpack16_fp8(v1, tmp);
#pragma unroll
            for (int l = 0; l < 16; ++l) acc[l] += tmp[l];
            unpack16_fp8(v2, tmp);
#pragma unroll
            for (int l = 0; l < 16; ++l) acc[l] += tmp[l];
            unpack16_fp8(v3, tmp);
#pragma unroll
            for (int l = 0; l < 16; ++l) acc[l] += tmp[l];
        }
        for (; k < e; ++k) {
            unpack16_fp8(Trow[((size_t)sp[k] << 3) + j], tmp);
#pragma unroll
            for (int l = 0; l < 16; ++l) acc[l] += tmp[l];
        }
    }
#pragma unroll
    for (int l = 0; l < 16; ++l) hl[n * 96 + j * 16 + l] = di * acc[l];
    __syncthreads();

    if (tid < 96) {
        int f = tid;
        float s = 0.0f;
        int gcur = -2;
        for (int nn = 0; nn < 32; ++nn) {
            int g = g_l[nn];
            if (g < 0) continue;
            if (g != gcur) {
                if (gcur >= 0) atomicAdd(&pooled[gcur * 96 + f], s);
                gcur = g;
                s = 0.0f;
            }
            s += hl[nn * 96 + f];
        }
        if (gcur >= 0) atomicAdd(&pooled[gcur * 96 + f], s);
    }
}

// ============ head: logits = (pooled/count + b2) @ Wf^T + bf ; log_softmax ============
// counts come precomputed from fill_kernel (no cold binary search).
__global__ void head_kernel(const float* __restrict__ pooled, const int* __restrict__ gcount,
                            const float* __restrict__ b2, const float* __restrict__ Wf,
                            const float* __restrict__ bfv, float* __restrict__ out) {
    __shared__ float wfs[OUT_DIM * HID];
    __shared__ float b2s[HID];
    __shared__ float bfs[OUT_DIM];
    int t = threadIdx.x;
    for (int idx = t; idx < OUT_DIM * HID; idx += 128) wfs[idx] = Wf[idx];
    if (t < HID) b2s[t] = b2[t];
    if (t < OUT_DIM) bfs[t] = bfv[t];
    __syncthreads();
    int g = t;
    if (g >= N_GRAPHS) return;
    int c = gcount[g];
    float inv = (c > 0) ? 1.0f / (float)c : 0.0f;
    float hasb = (c > 0) ? 1.0f : 0.0f;
    float logits[OUT_DIM];
#pragma unroll
    for (int o = 0; o < OUT_DIM; ++o) {
        float s = 0.0f;
        for (int cc = 0; cc < HID; ++cc)
            s += (pooled[g * HID + cc] * inv + hasb * b2s[cc]) * wfs[o * HID + cc];
        logits[o] = s + bfs[o];
    }
    float m = logits[0];
#pragma unroll
    for (int o = 1; o < OUT_DIM; ++o) m = fmaxf(m, logits[o]);
    float se = 0.0f;
#pragma unroll
    for (int o = 0; o < OUT_DIM; ++o) se += expf(logits[o] - m);
    float lse = m + logf(se);
#pragma unroll
    for (int o = 0; o < OUT_DIM; ++o) out[g * OUT_DIM + o] = logits[o] - lse;
}

extern "C" void kernel_launch(void* const* d_in, const int* in_sizes, int n_in,
                              void* d_out, int out_size, void* d_ws, size_t ws_size,
                              hipStream_t stream) {
    const float* x     = (const float*)d_in[0];
    const int*   ei    = (const int*)d_in[1];
    const int*   batch = (const int*)d_in[2];
    const float* W1    = (const float*)d_in[3];
    const float* b1    = (const float*)d_in[4];
    const float* W2    = (const float*)d_in[5];
    const float* b2    = (const float*)d_in[6];
    const float* Wf    = (const float*)d_in[7];
    const float* bf    = (const float*)d_in[8];

    const int N = in_sizes[0] / 128;  // 50000
    const int E = in_sizes[1] / 2;    // 800000
    const int* rowi = ei;
    const int* coli = ei + E;

    // workspace carve (256B aligned); cnt + pooled + gcount FIRST so one memset zeroes all
    size_t off = 0;
    auto alloc = [&](size_t bytes) {
        void* p = (char*)d_ws + off;
        off += (bytes + 255) & ~(size_t)255;
        return p;
    };
    int*            cnt    = (int*)alloc((size_t)N * 4);
    float*          pooled = (float*)alloc((size_t)N_GRAPHS * HID * 4);
    int*            gcount = (int*)alloc((size_t)N_GRAPHS * 4);
    size_t zero_bytes = off;  // covers cnt + pooled + gcount
    unsigned short* srcs   = (unsigned short*)alloc((size_t)N * CAP * 2);  // 6.4 MB
    unsigned char*  Tp1    = (unsigned char*)alloc((size_t)N * TROW);      // fp8 padded, 6.4 MB
    unsigned char*  Tp2    = (unsigned char*)alloc((size_t)N * TROW);      // fp8 padded, 6.4 MB

    hipMemsetAsync(d_ws, 0, zero_bytes, stream);

    // CSR bucket build (XCD-partitioned) + per-graph histogram
    const int nchunk = (E + 2047) / 2048;  // 391
    fill_kernel<<<nchunk * 8, 256, 0, stream>>>(rowi, coli, batch, cnt, gcount, srcs, E, N);

    // layer 1 transform
    gemm1_mfma<<<(N + 63) / 64, 256, 0, stream>>>(x, W1, cnt, Tp1, N);

    // layer 1 aggregate + layer 2 transform (fused), 64 nodes/block
    gather1_gemm2<<<(N + 63) / 64, 256, 0, stream>>>(Tp1, srcs, cnt, b1, W2, Tp2, N);

    // layer 2 aggregate + pool
    gather2_pool<<<(N + 31) / 32, 192, 0, stream>>>(Tp2, srcs, cnt, batch, pooled, N);

    // head
    head_kernel<<<1, 128, 0, stream>>>(pooled, gcount, b2, Wf, bf, (float*)d_out);
}

// Round 7
// 208.762 us; speedup vs baseline: 1.5283x; 1.5283x over previous
//
#include <hip/hip_runtime.h>
#include <hip/hip_bf16.h>

#define N_GRAPHS 128
#define HID 96
#define OUT_DIM 10
#define CAP 64   // per-node in-edge bucket; deg ~ Poisson(16), P(>=64) ~ 1e-22/node
#define TROW 128 // fp8 row pitch, padded 96 -> 128: one aligned 128B line per row

typedef __attribute__((ext_vector_type(8))) short short8;
typedef __attribute__((ext_vector_type(4))) float f32x4;
typedef __attribute__((ext_vector_type(2))) float f32x2;

// fp32 -> bf16 round-to-nearest-even
__device__ inline unsigned short f2bf(float f) {
    union { float f; unsigned u; } x;
    x.f = f;
    unsigned r = x.u + 0x7FFFu + ((x.u >> 16) & 1u);
    return (unsigned short)(r >> 16);
}

// fp32 -> fp8 e4m3 (OCP, HW convert), one byte
__device__ inline unsigned char f2fp8(float v) {
    int p = __builtin_amdgcn_cvt_pk_fp8_f32(v, v, 0, false);
    return (unsigned char)(p & 0xff);
}

// unpack 16 fp8 (uint4) -> 16 floats
__device__ inline void unpack16_fp8(uint4 v, float* o) {
    f32x2 a0 = __builtin_amdgcn_cvt_pk_f32_fp8((int)v.x, false);
    f32x2 a1 = __builtin_amdgcn_cvt_pk_f32_fp8((int)v.x, true);
    f32x2 b0 = __builtin_amdgcn_cvt_pk_f32_fp8((int)v.y, false);
    f32x2 b1 = __builtin_amdgcn_cvt_pk_f32_fp8((int)v.y, true);
    f32x2 c0 = __builtin_amdgcn_cvt_pk_f32_fp8((int)v.z, false);
    f32x2 c1 = __builtin_amdgcn_cvt_pk_f32_fp8((int)v.z, true);
    f32x2 d0 = __builtin_amdgcn_cvt_pk_f32_fp8((int)v.w, false);
    f32x2 d1 = __builtin_amdgcn_cvt_pk_f32_fp8((int)v.w, true);
    o[0] = a0.x;  o[1] = a0.y;  o[2] = a1.x;  o[3] = a1.y;
    o[4] = b0.x;  o[5] = b0.y;  o[6] = b1.x;  o[7] = b1.y;
    o[8] = c0.x;  o[9] = c0.y;  o[10] = c1.x; o[11] = c1.y;
    o[12] = d0.x; o[13] = d0.y; o[14] = d1.x; o[15] = d1.y;
}

// ============ XCD-partitioned CSR bucket fill + run-length per-graph counts ============
// block b: partition p = b&7 (dst range [N*p/8, N*(p+1)/8)), edge chunk b>>3 (2048 edges).
// Histogram: batch is SORTED -> threads scan 64-node chunks, one atomicAdd per run
// (~1.5K atomics total vs 50K contended per-node atomics, which cost +115us in R5).
__global__ __launch_bounds__(256) void fill_kernel(const int* __restrict__ rowi,
                                                   const int* __restrict__ coli,
                                                   const int* __restrict__ batch,
                                                   int* __restrict__ cnt,
                                                   int* __restrict__ gcount,
                                                   unsigned short* __restrict__ srcs,
                                                   int E, int N) {
    const int part = blockIdx.x & 7;
    const int chunk = blockIdx.x >> 3;
    const int base = chunk * 2048;
    const int plo = (int)(((long long)N * part) >> 3);
    const int phi = (int)(((long long)N * (part + 1)) >> 3);
#pragma unroll
    for (int it = 0; it < 8; ++it) {
        int e = base + it * 256 + threadIdx.x;
        if (e < E) {
            int c = coli[e];
            if (c >= plo && c < phi) {
                int pos = atomicAdd(&cnt[c], 1);
                if (pos < CAP) srcs[(size_t)c * CAP + pos] = (unsigned short)rowi[e];
            }
        }
    }
    // per-graph node counts via run-length over sorted batch (64 nodes/thread)
    const int gtid = blockIdx.x * 256 + threadIdx.x;
    const int nch = (N + 63) >> 6;
    if (gtid < nch) {
        const int i0 = gtid << 6;
        const int lim = min(64, N - i0);
        int gcur = batch[i0];
        int run = 0;
        for (int i = 0; i < lim; ++i) {
            int g = batch[i0 + i];
            if (g != gcur) {
                atomicAdd(&gcount[gcur], run);
                gcur = g;
                run = 0;
            }
            ++run;
        }
        atomicAdd(&gcount[gcur], run);
    }
}

// ============ gemm1: Tp1[N x TROW](fp8) = d[:,None] * (x[N x 128] @ W1[128 x 96]) ============
__global__ __launch_bounds__(256) void gemm1_mfma(const float* __restrict__ X,
                                                  const float* __restrict__ W,
                                                  const int* __restrict__ cnt,
                                                  unsigned char* __restrict__ Tp, int N) {
    constexpr int K = 128;
    constexpr int P = K + 8;
    constexpr int KT = K / 32;
    __shared__ __align__(16) unsigned short Wt[96 * P];
    const int tid = threadIdx.x;
    const int row0 = blockIdx.x * 64;

    for (int idx = tid; idx < K * 96; idx += 256) {
        int k = idx / 96, n = idx - k * 96;
        Wt[n * P + k] = f2bf(W[idx]);
    }
    __syncthreads();

    const int wv = tid >> 6;
    const int lane = tid & 63;
    const int m = lane & 15;
    const int quad = lane >> 4;
    const int row = row0 + wv * 16 + m;

    short8 afrag[KT];
    if (row < N) {
        const float* Xr = X + (size_t)row * K;
#pragma unroll
        for (int t = 0; t < KT; ++t) {
            float4 a0 = *(const float4*)(Xr + t * 32 + quad * 8);
            float4 a1 = *(const float4*)(Xr + t * 32 + quad * 8 + 4);
            short8 a;
            a[0] = (short)f2bf(a0.x); a[1] = (short)f2bf(a0.y);
            a[2] = (short)f2bf(a0.z); a[3] = (short)f2bf(a0.w);
            a[4] = (short)f2bf(a1.x); a[5] = (short)f2bf(a1.y);
            a[6] = (short)f2bf(a1.z); a[7] = (short)f2bf(a1.w);
            afrag[t] = a;
        }
    } else {
#pragma unroll
        for (int t = 0; t < KT; ++t) afrag[t] = short8{0, 0, 0, 0, 0, 0, 0, 0};
    }

    f32x4 acc[6];
#pragma unroll
    for (int nt = 0; nt < 6; ++nt) acc[nt] = f32x4{0.f, 0.f, 0.f, 0.f};
#pragma unroll
    for (int t = 0; t < KT; ++t) {
#pragma unroll
        for (int nt = 0; nt < 6; ++nt) {
            short8 bfrag = *(const short8*)&Wt[(nt * 16 + m) * P + t * 32 + quad * 8];
            acc[nt] = __builtin_amdgcn_mfma_f32_16x16x32_bf16(afrag[t], bfrag, acc[nt], 0, 0, 0);
        }
    }
#pragma unroll
    for (int r = 0; r < 4; ++r) {
        int orow = row0 + wv * 16 + quad * 4 + r;
        if (orow < N) {
            float d = rsqrtf(1.0f + (float)cnt[orow]);
#pragma unroll
            for (int nt = 0; nt < 6; ++nt)
                Tp[(size_t)orow * TROW + nt * 16 + m] = f2fp8(d * acc[nt][r]);
        }
    }
}

// ============ FUSED gather1 + gemm2 — 64 nodes/block (782 blocks => ~3/CU for latency hiding) ====
// Phase A: gather layer-1 aggregate -> H tile in LDS (bf16), 6 lanes x 16B per node.
//   H[i] = relu(d_i * (sum_src Tp1[s] + Tp1[i]) + b1)   (Tp1 pre-scaled by d_src)
// Phase B: MFMA  Tp2[i] = fp8(d_i * (H[i] @ W2)); wave wv owns row-tile wv (16 rows).
__global__ __launch_bounds__(256) void gather1_gemm2(const unsigned char* __restrict__ Tp1,
                                                     const unsigned short* __restrict__ srcs,
                                                     const int* __restrict__ cnt,
                                                     const float* __restrict__ b1,
                                                     const float* __restrict__ W2,
                                                     unsigned char* __restrict__ Tp2, int N) {
    constexpr int PH = 104;  // Hs pitch (shorts)
    constexpr int PW = 104;  // Wt pitch (shorts)
    __shared__ __align__(16) unsigned short Hs[64 * PH];   // 13312 B
    __shared__ __align__(16) unsigned short Wt[96 * PW];   // 19968 B  (total 33280 B -> 4 blocks/CU LDS cap)
    const int tid = threadIdx.x;
    const int node0 = blockIdx.x * 64;

    // stage W2^T (bf16) — no dependency on phase A
    for (int idx = tid; idx < 96 * 96; idx += 256) {
        int k = idx / 96, n = idx - k * 96;
        Wt[n * PW + k] = f2bf(W2[idx]);
    }

    // Phase A: gather. 64 nodes x 6 lanes = 384 items = 1.5 x 256.
    const uint4* Trow = (const uint4*)Tp1;  // 8 uint4 per padded fp8 row (j = 0..5 used)
#pragma unroll
    for (int it = 0; it < 2; ++it) {
        int idx = it * 256 + tid;
        if (idx < 384) {
            int n = idx / 6, j = idx - n * 6;
            int i = node0 + n;
            if (i < N) {
                float acc[16], tmp[16];
                unpack16_fp8(Trow[((size_t)i << 3) + j], acc);  // self-loop term
                int ci = cnt[i];
                int e = min(ci, CAP);
                const unsigned short* sp = srcs + (size_t)i * CAP;
                int k = 0;
                for (; k + 4 <= e; k += 4) {
                    ushort4 s4 = *(const ushort4*)(sp + k);
                    uint4 v0 = Trow[((size_t)s4.x << 3) + j];
                    uint4 v1 = Trow[((size_t)s4.y << 3) + j];
                    uint4 v2 = Trow[((size_t)s4.z << 3) + j];
                    uint4 v3 = Trow[((size_t)s4.w << 3) + j];
                    unpack16_fp8(v0, tmp);
#pragma unroll
                    for (int l = 0; l < 16; ++l) acc[l] += tmp[l];
                    unpack16_fp8(v1, tmp);
#pragma unroll
                    for (int l = 0; l < 16; ++l) acc[l] += tmp[l];
                    unpack16_fp8(v2, tmp);
#pragma unroll
                    for (int l = 0; l < 16; ++l) acc[l] += tmp[l];
                    unpack16_fp8(v3, tmp);
#pragma unroll
                    for (int l = 0; l < 16; ++l) acc[l] += tmp[l];
                }
                for (; k < e; ++k) {
                    unpack16_fp8(Trow[((size_t)sp[k] << 3) + j], tmp);
#pragma unroll
                    for (int l = 0; l < 16; ++l) acc[l] += tmp[l];
                }
                float di = rsqrtf(1.0f + (float)ci);
#pragma unroll
                for (int l = 0; l < 16; ++l) {
                    float v = fmaxf(di * acc[l] + b1[j * 16 + l], 0.0f);
                    Hs[n * PH + j * 16 + l] = f2bf(v);
                }
            } else {
#pragma unroll
                for (int l = 0; l < 16; ++l) Hs[n * PH + j * 16 + l] = 0;
            }
        }
    }
    __syncthreads();

    // Phase B: 4 row-tiles of 16; wave wv owns tile wv.
    const int wv = tid >> 6;
    const int lane = tid & 63;
    const int m = lane & 15;
    const int quad = lane >> 4;
    const int lrow = wv * 16 + m;
    short8 afrag[3];
#pragma unroll
    for (int t = 0; t < 3; ++t)
        afrag[t] = *(const short8*)&Hs[lrow * PH + t * 32 + quad * 8];
    f32x4 acc[6];
#pragma unroll
    for (int nt = 0; nt < 6; ++nt) acc[nt] = f32x4{0.f, 0.f, 0.f, 0.f};
#pragma unroll
    for (int t = 0; t < 3; ++t) {
#pragma unroll
        for (int nt = 0; nt < 6; ++nt) {
            short8 bfrag = *(const short8*)&Wt[(nt * 16 + m) * PW + t * 32 + quad * 8];
            acc[nt] = __builtin_amdgcn_mfma_f32_16x16x32_bf16(afrag[t], bfrag, acc[nt], 0, 0, 0);
        }
    }
#pragma unroll
    for (int r = 0; r < 4; ++r) {
        int orow = node0 + wv * 16 + quad * 4 + r;
        if (orow < N) {
            float d = rsqrtf(1.0f + (float)cnt[orow]);
#pragma unroll
            for (int nt = 0; nt < 6; ++nt)
                Tp2[(size_t)orow * TROW + nt * 16 + m] = f2fp8(d * acc[nt][r]);
        }
    }
}

// ============ gather2 + pool: pooled[batch[i]] += d_i*(sum Tp2[s] + Tp2[i])  (b2 in head) ====
// 192 threads = 32 nodes x 6 lanes (exactly one pass); LDS per-graph reduction.
__global__ __launch_bounds__(192) void gather2_pool(const unsigned char* __restrict__ Tp,
                                                    const unsigned short* __restrict__ srcs,
                                                    const int* __restrict__ cnt,
                                                    const int* __restrict__ batch,
                                                    float* __restrict__ pooled, int N) {
    __shared__ float hl[32 * 96];
    __shared__ int g_l[32];
    const int tid = threadIdx.x;
    const int n = tid / 6;
    const int j = tid - n * 6;
    const int i = blockIdx.x * 32 + n;
    if (tid < 32) {
        int ii = blockIdx.x * 32 + tid;
        g_l[tid] = (ii < N) ? batch[ii] : -1;
    }

    float acc[16];
#pragma unroll
    for (int l = 0; l < 16; ++l) acc[l] = 0.0f;
    float di = 0.0f;
    if (i < N) {
        const uint4* Trow = (const uint4*)Tp;  // 8 uint4 per padded row
        float tmp[16];
        unpack16_fp8(Trow[((size_t)i << 3) + j], acc);  // self
        int ci = cnt[i];
        di = rsqrtf(1.0f + (float)ci);
        int e = min(ci, CAP);
        const unsigned short* sp = srcs + (size_t)i * CAP;
        int k = 0;
        for (; k + 4 <= e; k += 4) {
            ushort4 s4 = *(const ushort4*)(sp + k);
            uint4 v0 = Trow[((size_t)s4.x << 3) + j];
            uint4 v1 = Trow[((size_t)s4.y << 3) + j];
            uint4 v2 = Trow[((size_t)s4.z << 3) + j];
            uint4 v3 = Trow[((size_t)s4.w << 3) + j];
            unpack16_fp8(v0, tmp);
#pragma unroll
            for (int l = 0; l < 16; ++l) acc[l] += tmp[l];
            unpack16_fp8(v1, tmp);
#pragma unroll
            for (int l = 0; l < 16; ++l) acc[l] += tmp[l];
            unpack16_fp8(v2, tmp);
#pragma unroll
            for (int l = 0; l < 16; ++l) acc[l] += tmp[l];
            unpack16_fp8(v3, tmp);
#pragma unroll
            for (int l = 0; l < 16; ++l) acc[l] += tmp[l];
        }
        for (; k < e; ++k) {
            unpack16_fp8(Trow[((size_t)sp[k] << 3) + j], tmp);
#pragma unroll
            for (int l = 0; l < 16; ++l) acc[l] += tmp[l];
        }
    }
#pragma unroll
    for (int l = 0; l < 16; ++l) hl[n * 96 + j * 16 + l] = di * acc[l];
    __syncthreads();

    if (tid < 96) {
        int f = tid;
        float s = 0.0f;
        int gcur = -2;
        for (int nn = 0; nn < 32; ++nn) {
            int g = g_l[nn];
            if (g < 0) continue;
            if (g != gcur) {
                if (gcur >= 0) atomicAdd(&pooled[gcur * 96 + f], s);
                gcur = g;
                s = 0.0f;
            }
            s += hl[nn * 96 + f];
        }
        if (gcur >= 0) atomicAdd(&pooled[gcur * 96 + f], s);
    }
}

// ============ head: logits = (pooled/count + b2) @ Wf^T + bf ; log_softmax ============
// counts come precomputed from fill_kernel (no cold binary search).
__global__ void head_kernel(const float* __restrict__ pooled, const int* __restrict__ gcount,
                            const float* __restrict__ b2, const float* __restrict__ Wf,
                            const float* __restrict__ bfv, float* __restrict__ out) {
    __shared__ float wfs[OUT_DIM * HID];
    __shared__ float b2s[HID];
    __shared__ float bfs[OUT_DIM];
    int t = threadIdx.x;
    for (int idx = t; idx < OUT_DIM * HID; idx += 128) wfs[idx] = Wf[idx];
    if (t < HID) b2s[t] = b2[t];
    if (t < OUT_DIM) bfs[t] = bfv[t];
    __syncthreads();
    int g = t;
    if (g >= N_GRAPHS) return;
    int c = gcount[g];
    float inv = (c > 0) ? 1.0f / (float)c : 0.0f;
    float hasb = (c > 0) ? 1.0f : 0.0f;
    float logits[OUT_DIM];
#pragma unroll
    for (int o = 0; o < OUT_DIM; ++o) {
        float s = 0.0f;
        for (int cc = 0; cc < HID; ++cc)
            s += (pooled[g * HID + cc] * inv + hasb * b2s[cc]) * wfs[o * HID + cc];
        logits[o] = s + bfs[o];
    }
    float m = logits[0];
#pragma unroll
    for (int o = 1; o < OUT_DIM; ++o) m = fmaxf(m, logits[o]);
    float se = 0.0f;
#pragma unroll
    for (int o = 0; o < OUT_DIM; ++o) se += expf(logits[o] - m);
    float lse = m + logf(se);
#pragma unroll
    for (int o = 0; o < OUT_DIM; ++o) out[g * OUT_DIM + o] = logits[o] - lse;
}

extern "C" void kernel_launch(void* const* d_in, const int* in_sizes, int n_in,
                              void* d_out, int out_size, void* d_ws, size_t ws_size,
                              hipStream_t stream) {
    const float* x     = (const float*)d_in[0];
    const int*   ei    = (const int*)d_in[1];
    const int*   batch = (const int*)d_in[2];
    const float* W1    = (const float*)d_in[3];
    const float* b1    = (const float*)d_in[4];
    const float* W2    = (const float*)d_in[5];
    const float* b2    = (const float*)d_in[6];
    const float* Wf    = (const float*)d_in[7];
    const float* bf    = (const float*)d_in[8];

    const int N = in_sizes[0] / 128;  // 50000
    const int E = in_sizes[1] / 2;    // 800000
    const int* rowi = ei;
    const int* coli = ei + E;

    // workspace carve (256B aligned); cnt + pooled + gcount FIRST so one memset zeroes all
    size_t off = 0;
    auto alloc = [&](size_t bytes) {
        void* p = (char*)d_ws + off;
        off += (bytes + 255) & ~(size_t)255;
        return p;
    };
    int*            cnt    = (int*)alloc((size_t)N * 4);
    float*          pooled = (float*)alloc((size_t)N_GRAPHS * HID * 4);
    int*            gcount = (int*)alloc((size_t)N_GRAPHS * 4);
    size_t zero_bytes = off;  // covers cnt + pooled + gcount
    unsigned short* srcs   = (unsigned short*)alloc((size_t)N * CAP * 2);  // 6.4 MB
    unsigned char*  Tp1    = (unsigned char*)alloc((size_t)N * TROW);      // fp8 padded, 6.4 MB
    unsigned char*  Tp2    = (unsigned char*)alloc((size_t)N * TROW);      // fp8 padded, 6.4 MB

    hipMemsetAsync(d_ws, 0, zero_bytes, stream);

    // CSR bucket build (XCD-partitioned) + run-length per-graph histogram
    const int nchunk = (E + 2047) / 2048;  // 391
    fill_kernel<<<nchunk * 8, 256, 0, stream>>>(rowi, coli, batch, cnt, gcount, srcs, E, N);

    // layer 1 transform
    gemm1_mfma<<<(N + 63) / 64, 256, 0, stream>>>(x, W1, cnt, Tp1, N);

    // layer 1 aggregate + layer 2 transform (fused), 64 nodes/block
    gather1_gemm2<<<(N + 63) / 64, 256, 0, stream>>>(Tp1, srcs, cnt, b1, W2, Tp2, N);

    // layer 2 aggregate + pool
    gather2_pool<<<(N + 31) / 32, 192, 0, stream>>>(Tp2, srcs, cnt, batch, pooled, N);

    // head
    head_kernel<<<1, 128, 0, stream>>>(pooled, gcount, b2, Wf, bf, (float*)d_out);
}